// Round 3
// baseline (259.085 us; speedup 1.0000x reference)
//
#include <hip/hip_runtime.h>
#include <math.h>

#define B 32
#define L 2048
#define V 512
#define D 512
#define S_CTX 32     // l-split blocks per batch in the context kernel
#define CAP 512      // max unique masked positions per batch (nnz/batch = 512)

// ws layout (bytes):
//   0        : int flag (1 = sparse_indices is int64)
//   256      : int wcnt[B]
//   1024     : float scores[B*L]            (256 KB)
//   263168   : int   clist[B*CAP]           (64 KB)
//   328704   : float cval[B*CAP]            (64 KB)

// scores = -inf, c = 0, and detect the index dtype.
__global__ void k_init(float* __restrict__ scores, float* __restrict__ c,
                       const int* __restrict__ idx32, int nnz, int* __restrict__ flag) {
    int i = blockIdx.x * 256 + threadIdx.x;
    if (i < B * L) scores[i] = -INFINITY;
    if (i < B * D) c[i] = 0.f;
    if (i == 0) {
        // int64 encoding: odd int32 words in [nnz, 2*nnz) are high halves == 0.
        // int32 encoding: those words are idx1 values, random in [0, L).
        int all0 = 1;
        for (int k = 0; k < 64; ++k) {
            int w = nnz + 1 + 2 * k * (nnz / 128);
            if (idx32[w] != 0) all0 = 0;
        }
        *flag = all0;
    }
}

// scores[b,l] = dot(bdi[b,l,:], W2). One wave per nnz entry.
// The reference also adds coef*(DHS@W1.T@W2)[b] — a per-batch constant over
// the masked set; softmax is shift-invariant and scores are not an output,
// so the whole W1/DHS path drops out exactly.
// Duplicate entries write identical values -> benign race.
__global__ void k_scores(const float* __restrict__ bdi, const float* __restrict__ W2,
                         const void* __restrict__ idx, int nnz,
                         const int* __restrict__ flag, float* __restrict__ scores) {
    int wave = threadIdx.x >> 6, lane = threadIdx.x & 63;
    int e = blockIdx.x * 4 + wave;
    if (e >= nnz) return;
    int b, l;
    if (*flag) {
        const long long* q = (const long long*)idx;
        b = (int)q[e];
        l = (int)q[nnz + e];
    } else {
        const int* q = (const int*)idx;
        b = q[e];
        l = q[nnz + e];
    }
    const float4* row = (const float4*)(bdi + ((size_t)b * L + l) * V);
    const float4* w   = (const float4*)W2;
    float4 r0 = row[lane],      w0 = w[lane];
    float4 r1 = row[lane + 64], w1 = w[lane + 64];
    float acc = r0.x * w0.x + r0.y * w0.y + r0.z * w0.z + r0.w * w0.w
              + r1.x * w1.x + r1.y * w1.y + r1.z * w1.z + r1.w * w1.w;
    for (int off = 32; off; off >>= 1) acc += __shfl_down(acc, off, 64);
    if (lane == 0) scores[b * L + l] = acc;
}

// Per-batch masked softmax over L (off-pattern scores are -inf -> exp 0).
// Also emits a compact (l, alpha) list per batch for the context kernel.
__global__ void k_softmax(const float* __restrict__ scores, float* __restrict__ alpha,
                          int* __restrict__ clist, float* __restrict__ cval,
                          int* __restrict__ wcnt) {
    int b = blockIdx.x, tid = threadIdx.x;
    __shared__ float e_s[L];     // 8 KB
    __shared__ float red[256];
    __shared__ int cnt;
    if (tid == 0) cnt = 0;
    float m = -INFINITY;
    for (int l = tid; l < L; l += 256) {
        float s = scores[b * L + l];
        e_s[l] = s;
        m = fmaxf(m, s);
    }
    red[tid] = m;
    __syncthreads();
    for (int off = 128; off; off >>= 1) {
        if (tid < off) red[tid] = fmaxf(red[tid], red[tid + off]);
        __syncthreads();
    }
    m = red[0];
    __syncthreads();
    float sum = 0.f;
    for (int l = tid; l < L; l += 256) {
        float e = __expf(e_s[l] - m);   // exp(-inf - m) = 0 off-pattern
        e_s[l] = e;
        sum += e;
    }
    red[tid] = sum;
    __syncthreads();
    for (int off = 128; off; off >>= 1) {
        if (tid < off) red[tid] += red[tid + off];
        __syncthreads();
    }
    float inv = 1.f / red[0];
    __syncthreads();
    for (int l = tid; l < L; l += 256) {
        float e = e_s[l];
        float a = (e > 0.f) ? e * inv : 0.f;
        alpha[b * L + l] = a;
        if (a > 0.f) {
            int p = atomicAdd(&cnt, 1);
            clist[b * CAP + p] = l;
            cval[b * CAP + p]  = a;
        }
    }
    __syncthreads();
    if (tid == 0) wcnt[b] = cnt;
}

// c[b,:] += sum over this block's stride of the compact list of att[b,l,:]*a.
__global__ void k_context(const float* __restrict__ att,
                          const int* __restrict__ clist, const float* __restrict__ cval,
                          const int* __restrict__ wcnt, float* __restrict__ c) {
    int b = blockIdx.x / S_CTX, s = blockIdx.x % S_CTX;
    int n = wcnt[b];
    int d = threadIdx.x * 2;
    float2 acc = {0.f, 0.f};
    #pragma unroll 4
    for (int j = s; j < n; j += S_CTX) {
        int   l = clist[b * CAP + j];
        float a = cval[b * CAP + j];
        float2 v = *(const float2*)(att + ((size_t)b * L + l) * D + d);
        acc.x += a * v.x;
        acc.y += a * v.y;
    }
    if (s < n) {
        atomicAdd(&c[b * D + d],     acc.x);
        atomicAdd(&c[b * D + d + 1], acc.y);
    }
}

extern "C" void kernel_launch(void* const* d_in, const int* in_sizes, int n_in,
                              void* d_out, int out_size, void* d_ws, size_t ws_size,
                              hipStream_t stream) {
    const float* bdi  = (const float*)d_in[1];
    const float* att  = (const float*)d_in[2];
    const void*  sidx = d_in[3];
    const float* W2   = (const float*)d_in[6];

    float* out   = (float*)d_out;
    float* c     = out;            // [B, D]
    float* alpha = out + B * D;    // [B, L] (== [B,L,1])
    // element count of sparse_indices is 2*nnz regardless of int32/int64
    int nnz = in_sizes[3] / 2;

    char* ws = (char*)d_ws;
    int*   flag   = (int*)ws;
    int*   wcnt   = (int*)(ws + 256);
    float* scores = (float*)(ws + 1024);
    int*   clist  = (int*)(ws + 1024 + B * L * 4);
    float* cval   = (float*)(ws + 1024 + B * L * 4 + B * CAP * 4);

    k_init<<<(B * L + 255) / 256, 256, 0, stream>>>(scores, c, (const int*)sidx, nnz, flag);
    k_scores<<<(nnz + 3) / 4, 256, 0, stream>>>(bdi, W2, sidx, nnz, flag, scores);
    k_softmax<<<B, 256, 0, stream>>>(scores, alpha, clist, cval, wcnt);
    k_context<<<B * S_CTX, 256, 0, stream>>>(att, clist, cval, wcnt, c);
}